// Round 1
// 74.630 us; speedup vs baseline: 1.2705x; 1.2705x over previous
//
#include <hip/hip_runtime.h>
#include <math.h>

#define N 1024
#define B 32
#define JC 8            // k1 j-chunks per row
#define K1CHUNK 128     // N / JC
#define ICH 64          // i-elements per k2 block
#define NSL 16          // j-slices per i (tid & 15)
#define SIGMA 1.0f
#define FEPS 1.1920928955078125e-07f   // np.finfo(float32).eps
#define LOG2E 1.4426950408889634f

#if defined(__has_builtin) && __has_builtin(__builtin_amdgcn_exp2f)
#define EXP2F(x) __builtin_amdgcn_exp2f(x)
#else
#define EXP2F(x) exp2f(x)
#endif

// Monotone-increasing uint mapping of float (no NaNs in input).
__device__ __forceinline__ unsigned fkey(float f) {
    unsigned u = __float_as_uint(f);
    return (u & 0x80000000u) ? ~u : (u | 0x80000000u);
}

// K1: partial stable-descending-rank counts over j-chunks; per-row sum(a) -> row_sum.
// grid = B*JC blocks of 256. block bx -> row r = bx>>3, chunk jc = bx&7.
// rank_part layout: [jc][r][i]
// Rank condition (a_j > a_i) || (a_j == a_i && j < i) is folded into ONE u64
// compare: K = (fkey(a) << 32) | (N-1-idx);  K_j > K_i  <=>  rank condition.
__global__ __launch_bounds__(256) void k1_rank(const float* __restrict__ a,
                                               int* __restrict__ rank_part,
                                               float* __restrict__ row_sum) {
    const int bx = blockIdx.x;
    const int r = bx >> 3, jc = bx & 7;
    const int tid = threadIdx.x;
    const float* __restrict__ arow = a + r * N;

    __shared__ unsigned long long sK[K1CHUNK];
    if (tid < K1CHUNK) {
        const int jg = jc * K1CHUNK + tid;
        sK[tid] = ((unsigned long long)fkey(arow[jg]) << 32) |
                  (unsigned)(N - 1 - jg);
    }

    float ai[4];
    unsigned long long Ki[4];
    int ig[4];
#pragma unroll
    for (int k = 0; k < 4; k++) {
        ig[k] = tid + k * 256;
        ai[k] = arow[ig[k]];
        Ki[k] = ((unsigned long long)fkey(ai[k]) << 32) |
                (unsigned)(N - 1 - ig[k]);
    }
    __syncthreads();

    int cnt[4] = {0, 0, 0, 0};
#pragma unroll 4
    for (int j = 0; j < K1CHUNK; j++) {
        const unsigned long long Kj = sK[j];
#pragma unroll
        for (int k = 0; k < 4; k++) cnt[k] += (Kj > Ki[k]) ? 1 : 0;
    }
#pragma unroll
    for (int k = 0; k < 4; k++)
        rank_part[(jc * B + r) * N + ig[k]] = cnt[k];

    if (jc == 0) {  // per-row sum of a for the placeholder loss
        float s = ai[0] + ai[1] + ai[2] + ai[3];
#pragma unroll
        for (int off = 32; off >= 1; off >>= 1) s += __shfl_down(s, off, 64);
        __shared__ float wsum[4];
        if ((tid & 63) == 0) wsum[tid >> 6] = s;
        __syncthreads();
        if (tid == 0) row_sum[r] = wsum[0] + wsum[1] + wsum[2] + wsum[3];
    }
}

// K2: fused prep + pairwise gradient. grid = B*16 blocks of 1024.
// Phase A: rank -> ilr; ballot-histogram idcg; then SCATTER elements into LDS
// in y-DESCENDING order (slot = count(y > y_e) + stable rank within group).
// Phase B: thread owns SLOT us = ic*64 + tid>>4, slice s = tid&15. The j-loop
// splits into [0, lo) (y_j > y_u: selector is loop-invariant E_u, hoisted out)
// and [hi, N) (y_j < y_u: selector E_j). Same-label pairs (exactly zero
// contribution) are skipped entirely (~20% of all pairs), and the per-pair
// cmp+cndmask of the old kernel is gone.
// KEY (unchanged): 1/(1+exp(s*(a_i-a_j))) == (s>0 ? E_j : E_i)/(E_i+E_j).
__global__ __launch_bounds__(1024, 8) void k2_fused(const float* __restrict__ a,
                                                    const float* __restrict__ y,
                                                    const int* __restrict__ rank_part,
                                                    const float* __restrict__ row_sum,
                                                    float* __restrict__ out) {
    const int bx = blockIdx.x;
    const int r = bx >> 4, ic = bx & 15;
    const int tid = threadIdx.x;
    const int wid = tid >> 6, lane = tid & 63;

    __shared__ float4 sdat[N];          // y-sorted: (gain*c, ilr, e^a, orig idx)
    __shared__ int hist[16][4];
    __shared__ int cntW[16][5];         // per-wave per-label counts
    __shared__ int tot[4];              // tot[v] = count(y >= v+1)
    __shared__ float wt[16];
    __shared__ float sC;

    const float ai = a[r * N + tid];
    const float yi = y[r * N + tid];

    int cnt = 0;
#pragma unroll
    for (int jc = 0; jc < JC; jc++) cnt += rank_part[(jc * B + r) * N + tid];
    // pi = cnt+1; ilr = 1/log2(pi+1) = 1/log2(cnt+2)
    const float ilr = __builtin_amdgcn_rcpf(__log2f((float)(cnt + 2)));

    // histogram of y (0..4) via wave ballots (no LDS atomics)
    const unsigned long long b1 = __ballot(yi >= 1.0f);
    const unsigned long long b2 = __ballot(yi >= 2.0f);
    const unsigned long long b3 = __ballot(yi >= 3.0f);
    const unsigned long long b4 = __ballot(yi >= 4.0f);
    const unsigned long long m4 = b4;
    const unsigned long long m3 = b3 & ~b4;
    const unsigned long long m2 = b2 & ~b3;
    const unsigned long long m1 = b1 & ~b2;
    const unsigned long long m0 = ~b1;
    if (lane == 0) {
        hist[wid][0] = __popcll(b1);
        hist[wid][1] = __popcll(b2);
        hist[wid][2] = __popcll(b3);
        hist[wid][3] = __popcll(b4);
        cntW[wid][0] = __popcll(m0);
        cntW[wid][1] = __popcll(m1);
        cntW[wid][2] = __popcll(m2);
        cntW[wid][3] = __popcll(m3);
        cntW[wid][4] = __popcll(m4);
    }
    __syncthreads();
    if (tid < 4) {
        int t = 0;
#pragma unroll
        for (int w = 0; w < 16; w++) t += hist[w][tid];
        tot[tid] = t;
    }
    __syncthreads();
    const int p1 = tot[0], p2 = tot[1], p3 = tot[2], p4 = tot[3];
    // idcg from sorted-descending y at position tid
    const int vv = (tid < p4) ? 4 : (tid < p3) ? 3 : (tid < p2) ? 2 : (tid < p1) ? 1 : 0;
    float term = (float)((1 << vv) - 1) *
                 __builtin_amdgcn_rcpf(__log2f((float)(tid + 2)));
#pragma unroll
    for (int off = 32; off >= 1; off >>= 1) term += __shfl_down(term, off, 64);
    if (lane == 0) wt[wid] = term;
    __syncthreads();
    if (tid == 0) {
        float idcg = 0.f;
#pragma unroll
        for (int w = 0; w < 16; w++) idcg += wt[w];
        sC = 2.0f * SIGMA / (idcg + FEPS);
    }
    if (bx == 0 && wid == 0) {  // loss = sum(a): reduce K1's 32 row sums
        float s = (lane < B) ? row_sum[lane] : 0.f;
#pragma unroll
        for (int off = 16; off >= 1; off >>= 1) s += __shfl_down(s, off, 64);
        if (lane == 0) out[0] = s;
    }

    // scatter into y-descending slot order
    const int v = (int)yi;
    const unsigned long long mym = (v == 4) ? m4 : (v == 3) ? m3 : (v == 2) ? m2
                                 : (v == 1) ? m1 : m0;
    const int start = (v == 4) ? 0 : tot[v];         // count(y > v)
    int prefix = 0;
    for (int w = 0; w < wid; w++) prefix += cntW[w][v];
    const int slot = start + prefix +
                     __popcll(mym & ((1ull << lane) - 1ull));

    __syncthreads();
    const float c = sC;
    const float Ei = EXP2F(ai * LOG2E);              // e^a_i, once per element
    sdat[slot] = make_float4(EXP2F(yi) * c, ilr, Ei, __int_as_float(tid));
    __syncthreads();

    const int us = ic * ICH + (tid >> 4);            // owned SLOT
    const int s = tid & 15;
    const float4 du = sdat[us];
    // group bounds of slot us: regions [0,t3)=4,[t3,t2)=3,[t2,t1)=2,[t1,t0)=1,[t0,N)=0
    int lo, hi;
    if (us < p4)      { lo = 0;  hi = p4; }
    else if (us < p3) { lo = p4; hi = p3; }
    else if (us < p2) { lo = p3; hi = p2; }
    else if (us < p1) { lo = p2; hi = p1; }
    else              { lo = p1; hi = N;  }

    float acc1 = 0.f, acc2 = 0.f;
    // y_j > y_u: dg < 0, selector = E_u (hoisted out of the loop)
    for (int u = s; u < lo; u += NSL) {
        const float4 dj = sdat[u];
        const float dg = du.x - dj.x;
        const float dl = du.y - dj.y;
        const float p  = dg * fabsf(dl);
        const float sum = du.z + dj.z;
        acc1 = fmaf(p, __builtin_amdgcn_rcpf(sum), acc1);
    }
    // y_j < y_u: dg > 0, selector = E_j
    for (int u = hi + ((s - hi) & 15); u < N; u += NSL) {
        const float4 dj = sdat[u];
        const float dg = du.x - dj.x;
        const float dl = du.y - dj.y;
        const float p  = dg * fabsf(dl) * dj.z;
        const float sum = du.z + dj.z;
        acc2 = fmaf(p, __builtin_amdgcn_rcpf(sum), acc2);
    }
    float acc = fmaf(acc1, du.z, acc2);
#pragma unroll
    for (int off = 8; off >= 1; off >>= 1) acc += __shfl_down(acc, off, 16);
    if (s == 0) out[1 + r * N + __float_as_int(du.w)] = -acc;
}

extern "C" void kernel_launch(void* const* d_in, const int* in_sizes, int n_in,
                              void* d_out, int out_size, void* d_ws, size_t ws_size,
                              hipStream_t stream) {
    (void)in_sizes; (void)n_in; (void)out_size; (void)ws_size;
    const float* a = (const float*)d_in[0];
    const float* y = (const float*)d_in[1];
    float* out = (float*)d_out;

    int* rank_part = (int*)d_ws;                                    // 8*32*1024*4 = 1 MB
    float* row_sum = (float*)((char*)d_ws + (size_t)JC * B * N * sizeof(int)); // 128 B

    hipLaunchKernelGGL(k1_rank, dim3(B * JC), dim3(256), 0, stream, a, rank_part, row_sum);
    hipLaunchKernelGGL(k2_fused, dim3(B * 16), dim3(1024), 0, stream, a, y, rank_part,
                       row_sum, out);
}